// Round 5
// baseline (109.389 us; speedup 1.0000x reference)
//
#include <hip/hip_runtime.h>
#include <hip/hip_fp16.h>

#define VOC    512
#define EMB    128
#define L_SEQ  32
#define NWORDS 16384
#define NCOL   416
#define WPB    128         // words per conv word-group
#define SUBW   32          // subtable row width (halves)
#define SUBSTRIDE_H 16416  // 513*32 halves per subtable
#define SCP    40          // sc row pitch in u16 (80 B)

// pe: 13 subtables of 513 rows x 32 halves (row VOC=512 all-zero).
// Filter-pair INTERLEAVED layout for segs 0-2 (packed float2 accumulation):
//   seg0 (k2): sub 0,  loc = (ol>>1)*4 + j*2 + (ol&1)
//   seg1 (k3): sub 1+(ol>>3), loc = ((ol&7)>>1)*8 + j*2 + (ol&1)
//   seg2 (k4): sub 3+(ol>>3), same formula
//   seg3 (k5): sub 5+(ol>>2), loc = (ol&3)*8 + j   (filter-major)
//   seg4 (k6): sub 9+(ol>>2), loc = (ol&3)*8 + j

// -------- Kernel 1: fused pack+build, 2 chars per block ------------------
__global__ __launch_bounds__(512) void build_pe(
    const float* __restrict__ emb,
    const float* __restrict__ w2, const float* __restrict__ w3,
    const float* __restrict__ w4, const float* __restrict__ w5,
    const float* __restrict__ w6,
    __half* __restrict__ pe)
{
    __shared__ float e[2][EMB];
    const int tid = threadIdx.x;
    const int c0  = blockIdx.x * 2;
    if (tid < 2 * EMB) {
        const int ch = tid >> 7, i = tid & 127, c = c0 + ch;
        e[ch][i] = (c < VOC) ? emb[c * EMB + i] : 0.f;   // c>=VOC -> zero row
    }
    __syncthreads();
    const int col = tid;
    if (col >= NCOL) return;

    int k, jpad, base, seg; const float* w;
    if (col < 32)       { k = 2; jpad = 2; base = 0;   seg = 0; w = w2; }
    else if (col < 96)  { k = 3; jpad = 4; base = 32;  seg = 1; w = w3; }
    else if (col < 160) { k = 4; jpad = 4; base = 96;  seg = 2; w = w4; }
    else if (col < 288) { k = 5; jpad = 8; base = 160; seg = 3; w = w5; }
    else                { k = 6; jpad = 8; base = 288; seg = 4; w = w6; }

    const int r  = col - base;
    const int ol = (jpad == 2) ? (r >> 1) : (jpad == 4) ? (r >> 2) : (r >> 3);
    const int j  = r & (jpad - 1);

    int sub, loc;
    if (seg == 0)      { sub = 0;           loc = (ol >> 1) * 4 + j * 2 + (ol & 1); }
    else if (seg == 1) { sub = 1 + (ol>>3); loc = ((ol & 7) >> 1) * 8 + j * 2 + (ol & 1); }
    else if (seg == 2) { sub = 3 + (ol>>3); loc = ((ol & 7) >> 1) * 8 + j * 2 + (ol & 1); }
    else if (seg == 3) { sub = 5 + (ol>>2); loc = (ol & 3) * 8 + j; }
    else               { sub = 9 + (ol>>2); loc = (ol & 3) * 8 + j; }

    float a0 = 0.f, a1 = 0.f;
    if (j < k) {                            // padded taps stay zero
        const float* wp = w + (ol * EMB) * k + j;
        #pragma unroll 8
        for (int i = 0; i < EMB; ++i) {
            const float wv = wp[i * k];     // w[(ol*EMB+i)*k + j]
            a0 += wv * e[0][i]; a1 += wv * e[1][i];
        }
    }
    const int bb = sub * SUBSTRIDE_H + loc;
    pe[bb + c0 * SUBW] = __float2half(a0);
    if (c0 + 1 <= VOC) pe[bb + (c0 + 1) * SUBW] = __float2half(a1);
}

// -------- Kernel 2: persistent-sub blocks, 2 word-groups each ------------
__device__ __forceinline__ float2 h2tof2(int u) {
    return __half22float2(__builtin_bit_cast(__half2, u));
}

// Paired conv: flat bias-initialized float2 accumulators (2 filters).
template<int K, int PAD>
__device__ __forceinline__ float2 convP(const char* __restrict__ tbl,
                                        const unsigned short* __restrict__ sc,
                                        int w, float2 bias)
{
    constexpr int LOUT = L_SEQ + 2 * PAD - K + 1;
    int d[16];
    {
        const int4* sp = (const int4*)(sc + w * SCP);   // 80B pitch, aligned
        #pragma unroll
        for (int g = 0; g < 4; ++g) {
            const int4 s4 = sp[g];
            d[4*g] = s4.x; d[4*g+1] = s4.y; d[4*g+2] = s4.z; d[4*g+3] = s4.w;
        }
    }
    float2 s[LOUT];
    #pragma unroll
    for (int t = 0; t < LOUT; ++t) s[t] = bias;

    #pragma unroll
    for (int tp = 0; tp < 32; ++tp) {
        const int dw = d[tp >> 1];
        const int pm = (tp & 1) ? (int)(((unsigned)dw) >> 16) : (dw & 0xffff);
        if constexpr (K == 2) {
            const int2 qq = *(const int2*)(tbl + pm);
            const int W2[2] = {qq.x, qq.y};
            #pragma unroll
            for (int j = 0; j < 2; ++j) {
                const int t = tp - j;                   // PAD=0
                if (t >= 0 && t < LOUT) {
                    const float2 v = h2tof2(W2[j]);
                    s[t].x += v.x; s[t].y += v.y;
                }
            }
        } else {
            const int4 qq = *(const int4*)(tbl + pm);
            const int W4[4] = {qq.x, qq.y, qq.z, qq.w};
            #pragma unroll
            for (int j = 0; j < K; ++j) {               // K<=4 here
                const int t = tp + PAD - j;
                if (t >= 0 && t < LOUT) {
                    const float2 v = h2tof2(W4[j]);
                    s[t].x += v.x; s[t].y += v.y;
                }
            }
        }
    }
    float2 m = s[0];
    #pragma unroll
    for (int t = 1; t < LOUT; ++t) {
        m.x = fmaxf(m.x, s[t].x); m.y = fmaxf(m.y, s[t].y);
    }
    return m;
}

// Scalar conv: one filter, flat bias-initialized accumulators.
template<int K, int PAD>
__device__ __forceinline__ float convS(const char* __restrict__ tbl,
                                       const unsigned short* __restrict__ sc,
                                       int w, float bias)
{
    constexpr int LOUT = L_SEQ + 2 * PAD - K + 1;
    int d[16];
    {
        const int4* sp = (const int4*)(sc + w * SCP);
        #pragma unroll
        for (int g = 0; g < 4; ++g) {
            const int4 s4 = sp[g];
            d[4*g] = s4.x; d[4*g+1] = s4.y; d[4*g+2] = s4.z; d[4*g+3] = s4.w;
        }
    }
    float s[LOUT];
    #pragma unroll
    for (int t = 0; t < LOUT; ++t) s[t] = bias;

    #pragma unroll
    for (int tp = 0; tp < 32; ++tp) {
        const int dw = d[tp >> 1];
        const int pm = (tp & 1) ? (int)(((unsigned)dw) >> 16) : (dw & 0xffff);
        const int4 qq = *(const int4*)(tbl + pm);
        const int W4[4] = {qq.x, qq.y, qq.z, qq.w};
        float v[K];
        #pragma unroll
        for (int h = 0; h < (K + 1) / 2; ++h) {
            const float2 f = h2tof2(W4[h]);
            v[2*h] = f.x;
            if (2*h + 1 < K) v[2*h + 1] = f.y;
        }
        #pragma unroll
        for (int j = 0; j < K; ++j) {
            const int t = tp + PAD - j;
            if (t >= 0 && t < LOUT) s[t] += v[j];
        }
    }
    float m = s[0];
    #pragma unroll
    for (int t = 1; t < LOUT; ++t) m = fmaxf(m, s[t]);
    return m;
}

// Pack 8 chars (2 x int4) into one 16B LDS write of pre-multiplied u16s.
// For i = tid*8+u: row i>>5 == tid>>2, col i&31 == (tid&3)*8+u (contiguous).
__device__ __forceinline__ void sc_write(unsigned short* __restrict__ sc16,
                                         int tid, int4 a, int4 b)
{
    #define ENC(c) ((unsigned)((((c) >= 0) ? (c) : VOC) * 80))
    int4 o;
    o.x = (int)(ENC(a.x) | (ENC(a.y) << 16));
    o.y = (int)(ENC(a.z) | (ENC(a.w) << 16));
    o.z = (int)(ENC(b.x) | (ENC(b.y) << 16));
    o.w = (int)(ENC(b.z) | (ENC(b.w) << 16));
    #undef ENC
    *(int4*)(sc16 + (tid >> 2) * SCP + (tid & 3) * 8) = o;
}

__global__ __launch_bounds__(512, 4) void conv_max(
    const int*    __restrict__ word,
    const __half* __restrict__ pe,
    const float* __restrict__ b2, const float* __restrict__ b3,
    const float* __restrict__ b4, const float* __restrict__ b5,
    const float* __restrict__ b6,
    float*       __restrict__ out)
{
    // 41,040 B table (513 x 80 B pitch) + 10,240 B sc = 51,280 B -> 3/CU
    __shared__ __align__(16) __half tab[513 * 40];
    __shared__ __align__(16) unsigned short sc16[WPB * SCP];

    const int tid = threadIdx.x;
    const int wbp = blockIdx.x & 63;    // word-pair group; XCD = wbp%8 for all subs
    const int sub = blockIdx.x >> 6;    // 0..12
    const int wb0 = wbp, wb1 = wbp + 64;

    // stage subtable ONCE: 64B global rows -> 80B LDS pitch (bank-spread)
    {
        const int4* src = (const int4*)(pe + sub * SUBSTRIDE_H);
        char* tw = (char*)tab;
        for (int i = tid; i < 513 * 4; i += 512)
            *(int4*)(tw + (i >> 2) * 80 + (i & 3) * 16) = src[i];
    }
    // stage word-group 0 offsets (vectorized: 2 int4 loads -> 1 b128 write)
    {
        const int4* wp4 = (const int4*)(word + wb0 * (WPB * L_SEQ)) + tid * 2;
        sc_write(sc16, tid, wp4[0], wp4[1]);
    }
    __syncthreads();

    const char* tb = (const char*)tab;
    float* ob0 = out + wb0 * (WPB * 80);
    float* ob1 = out + wb1 * (WPB * 80);
    const int4* wp1 = (const int4*)(word + wb1 * (WPB * L_SEQ)) + tid * 2;

    if (sub == 0) {
        // 8 filter-pairs x 64 words, 2 words/thread, b64 taps
        const int p = tid & 7, w = tid >> 3;
        const char* tbl = tb + p * 8;
        const float2 bias = {b2[2*p], b2[2*p + 1]};
        float2 ma = convP<2, 0>(tbl, sc16, w,      bias);
        float2 mb = convP<2, 0>(tbl, sc16, w + 64, bias);
        *(float2*)(ob0 + w * 80 + 2*p)        = ma;
        *(float2*)(ob0 + (w + 64) * 80 + 2*p) = mb;
        __syncthreads();
        sc_write(sc16, tid, wp1[0], wp1[1]);
        __syncthreads();
        ma = convP<2, 0>(tbl, sc16, w,      bias);
        mb = convP<2, 0>(tbl, sc16, w + 64, bias);
        *(float2*)(ob1 + w * 80 + 2*p)        = ma;
        *(float2*)(ob1 + (w + 64) * 80 + 2*p) = mb;
    } else if (sub <= 4) {
        // 4 filter-pairs x 128 words, 1 word/thread, b128 taps
        const int fp = tid & 3, w = tid >> 2;
        const char* tbl = tb + fp * 16;
        const int half = (sub - 1) & 1;
        const bool is1 = (sub <= 2);
        const float* bp = is1 ? b3 : b4;
        const int f0 = half * 8 + 2 * fp;
        const float2 bias = {bp[f0], bp[f0 + 1]};
        const int oo = (is1 ? 16 : 32) + f0;
        float2 m;
        if (is1) m = convP<3, 0>(tbl, sc16, w, bias);
        else     m = convP<4, 1>(tbl, sc16, w, bias);
        *(float2*)(ob0 + w * 80 + oo) = m;
        __syncthreads();
        sc_write(sc16, tid, wp1[0], wp1[1]);
        __syncthreads();
        if (is1) m = convP<3, 0>(tbl, sc16, w, bias);
        else     m = convP<4, 1>(tbl, sc16, w, bias);
        *(float2*)(ob1 + w * 80 + oo) = m;
    } else if (sub <= 8) {
        // seg3 (k5): 4 filters x 128 words
        const int ol = tid & 3, w = tid >> 2;
        const char* tbl = tb + ol * 16;
        const int f = (sub - 5) * 4 + ol;
        const float bias = b5[f];
        float m = convS<5, 2>(tbl, sc16, w, bias);
        ob0[w * 80 + 48 + f] = m;
        __syncthreads();
        sc_write(sc16, tid, wp1[0], wp1[1]);
        __syncthreads();
        m = convS<5, 2>(tbl, sc16, w, bias);
        ob1[w * 80 + 48 + f] = m;
    } else {
        // seg4 (k6): 4 filters x 128 words
        const int ol = tid & 3, w = tid >> 2;
        const char* tbl = tb + ol * 16;
        const int f = (sub - 9) * 4 + ol;
        const float bias = b6[f];
        float m = convS<6, 3>(tbl, sc16, w, bias);
        ob0[w * 80 + 64 + f] = m;
        __syncthreads();
        sc_write(sc16, tid, wp1[0], wp1[1]);
        __syncthreads();
        m = convS<6, 3>(tbl, sc16, w, bias);
        ob1[w * 80 + 64 + f] = m;
    }
}

extern "C" void kernel_launch(void* const* d_in, const int* in_sizes, int n_in,
                              void* d_out, int out_size, void* d_ws, size_t ws_size,
                              hipStream_t stream)
{
    const int*   word = (const int*)  d_in[0];
    const float* emb  = (const float*)d_in[1];
    const float* w2   = (const float*)d_in[2];
    const float* b2   = (const float*)d_in[3];
    const float* w3   = (const float*)d_in[4];
    const float* b3   = (const float*)d_in[5];
    const float* w4   = (const float*)d_in[6];
    const float* b4   = (const float*)d_in[7];
    const float* w5   = (const float*)d_in[8];
    const float* b5   = (const float*)d_in[9];
    const float* w6   = (const float*)d_in[10];
    const float* b6   = (const float*)d_in[11];
    float* out = (float*)d_out;

    __half* pe16 = (__half*)d_ws;   // 13 * 16416 halves = 426,816 B

    build_pe<<<257, 512, 0, stream>>>(emb, w2, w3, w4, w5, w6, pe16);

    conv_max<<<13 * 64, 512, 0, stream>>>(
        word, pe16, b2, b3, b4, b5, b6, out);
}